// Round 3
// baseline (389.695 us; speedup 1.0000x reference)
//
#include <hip/hip_runtime.h>
#include <math.h>

#define NRAYS 512
#define NSAMP 64
#define NVIEW 2
#define IMH 480
#define IMW 640
#define NFEAT 256
#define XROW 268   // 265-dim x row, padded to 67 float4 slots (16B-aligned stride)
#define HROW 132   // 128-dim h1 row, 16B-aligned stride
#define ZNEAR 0.7f
#define ZFAR 1.5f

// Kernel A: one block per (ray, view). 512 threads = 8 waves; wave g owns
// output channels [16g, 16g+16). lane = sample. Weights are loaded through an
// opaque per-lane address (asm zero) so they go down the VMEM path
// (global_load_dwordx4, vmcnt-pipelined) instead of SMEM s_load, whose
// out-of-order returns force lgkmcnt(0) drains against the x ds_reads.
__global__ __launch_bounds__(512, 4)
void nerf_mlp(const float* __restrict__ rayo,
              const float* __restrict__ rayd,
              const float* __restrict__ images,
              const float* __restrict__ intr,
              const float* __restrict__ einv,
              const float* __restrict__ feats,
              const float* __restrict__ W1,
              const float* __restrict__ b1,
              const float* __restrict__ W2,
              const float* __restrict__ b2,
              const float* __restrict__ Wr,
              float* __restrict__ wsout)
{
    __shared__ float xb[NSAMP * XROW];          // x-matrix; h1 (64xHROW) overlays after L1
    __shared__ float partials[8][NSAMP][4];
    __shared__ int   s_off[NSAMP][4];
    __shared__ float s_wxy[NSAMP][2];
    __shared__ float s_cam[NSAMP][4];
    __shared__ float s_cdir[4];

    const int t = threadIdx.x;
    const int bid = blockIdx.x;
    const int r = bid >> 1;
    const int v = bid & 1;
    const int lane = t & 63;                                  // sample index
    const int g = __builtin_amdgcn_readfirstlane(t >> 6);     // wave = 16-ch slice
    constexpr float STEP = (ZFAR - ZNEAR) / (NSAMP - 1);

    int vzero;                                                // opaque 0 in a VGPR
    asm volatile("v_mov_b32 %0, 0" : "=v"(vzero));

    const float ox = rayo[r*3+0], oy = rayo[r*3+1], oz = rayo[r*3+2];
    const float dx = rayd[r*3+0], dy = rayd[r*3+1], dz = rayd[r*3+2];

    // ---- per-sample projection prep ----
    if (t < NSAMP) {
        const int p = t;
        const float z = ZNEAR + p * STEP;
        const float wxp = ox + z*dx, wyp = oy + z*dy, wzp = oz + z*dz;
        const float* E = einv + v*16;
        const float cx = E[0]*wxp + E[1]*wyp + E[2]*wzp + E[3];
        const float cy = E[4]*wxp + E[5]*wyp + E[6]*wzp + E[7];
        const float cz = E[8]*wxp + E[9]*wyp + E[10]*wzp + E[11];
        const float cw = E[12]*wxp + E[13]*wyp + E[14]*wzp + E[15];
        const float* Km = intr + v*16;
        const float px = Km[0]*cx + Km[1]*cy + Km[2]*cz + Km[3]*cw;
        const float py = Km[4]*cx + Km[5]*cy + Km[6]*cz + Km[7]*cw;
        const float pz = Km[8]*cx + Km[9]*cy + Km[10]*cz + Km[11]*cw;
        const float inv = pz + 1e-8f;
        float fx = px / inv, fy = py / inv;
        fx = fminf(fmaxf(fx, 0.0f), (float)(IMW-1));
        fy = fminf(fmaxf(fy, 0.0f), (float)(IMH-1));
        const int x0 = (int)floorf(fx), y0 = (int)floorf(fy);
        const int x1 = min(x0+1, IMW-1), y1 = min(y0+1, IMH-1);
        const int base = v*IMH*IMW;
        s_off[p][0] = (base + y0*IMW + x0) * NFEAT;
        s_off[p][1] = (base + y0*IMW + x1) * NFEAT;
        s_off[p][2] = (base + y1*IMW + x0) * NFEAT;
        s_off[p][3] = (base + y1*IMW + x1) * NFEAT;
        s_wxy[p][0] = fx - (float)x0;
        s_wxy[p][1] = fy - (float)y0;
        s_cam[p][0] = cx; s_cam[p][1] = cy; s_cam[p][2] = cz;
        if (t == 0) {
            s_cdir[0] = E[0]*dx + E[1]*dy + E[2]*dz;
            s_cdir[1] = E[4]*dx + E[5]*dy + E[6]*dz;
            s_cdir[2] = E[8]*dx + E[9]*dy + E[10]*dz;
        }
    }
    __syncthreads();

    // ---- bilinear gather: 8 threads per sample, float4 chunks ----
    {
        const int s = t >> 3, k = t & 7;
        const int o00 = s_off[s][0], o01 = s_off[s][1];
        const int o10 = s_off[s][2], o11 = s_off[s][3];
        const float wxf = s_wxy[s][0], wyf = s_wxy[s][1];
        const float w00 = (1.f-wxf)*(1.f-wyf), w01 = wxf*(1.f-wyf);
        const float w10 = (1.f-wxf)*wyf,       w11 = wxf*wyf;
        float* xrow = xb + s * XROW;
        #pragma unroll
        for (int i = 0; i < 8; ++i) {
            const int c = k*32 + i*4;
            const float4 f00 = *reinterpret_cast<const float4*>(feats + o00 + c);
            const float4 f01 = *reinterpret_cast<const float4*>(feats + o01 + c);
            const float4 f10 = *reinterpret_cast<const float4*>(feats + o10 + c);
            const float4 f11 = *reinterpret_cast<const float4*>(feats + o11 + c);
            xrow[9+c+0] = w00*f00.x + w01*f01.x + w10*f10.x + w11*f11.x;
            xrow[9+c+1] = w00*f00.y + w01*f01.y + w10*f10.y + w11*f11.y;
            xrow[9+c+2] = w00*f00.z + w01*f01.z + w10*f10.z + w11*f11.z;
            xrow[9+c+3] = w00*f00.w + w01*f01.w + w10*f10.w + w11*f11.w;
        }
        if (k == 0) {
            const int i00 = (o00 >> 8) * 3, i01 = (o01 >> 8) * 3;
            const int i10 = (o10 >> 8) * 3, i11 = (o11 >> 8) * 3;
            #pragma unroll
            for (int ch = 0; ch < 3; ++ch) {
                const float bl = w00*images[i00+ch] + w01*images[i01+ch]
                               + w10*images[i10+ch] + w11*images[i11+ch];
                xrow[6+ch] = 2.0f*bl - 1.0f;
            }
            xrow[0] = s_cam[s][0]; xrow[1] = s_cam[s][1]; xrow[2] = s_cam[s][2];
        } else if (k == 1) {
            xrow[3] = s_cdir[0]; xrow[4] = s_cdir[1]; xrow[5] = s_cdir[2];
        }
    }
    __syncthreads();

    // ---- layer 1: wave g -> channels [16g,16g+16), lane = sample ----
    const int cb = g * 16;
    float acc[16];
    #pragma unroll
    for (int jj = 0; jj < 16; ++jj) acc[jj] = 0.0f;
    {
        const float* __restrict__ w1g = W1 + cb;
        const float* xrow = xb + lane * XROW;
        for (int d4 = 0; d4 < 66; ++d4) {
            const float4 xv = *reinterpret_cast<const float4*>(xrow + d4*4);
            const float xa[4] = {xv.x, xv.y, xv.z, xv.w};
            #pragma unroll
            for (int i = 0; i < 4; ++i) {
                const float* wrow = w1g + (d4*4 + i)*128 + vzero;  // VMEM path
                const float4 wa = *reinterpret_cast<const float4*>(wrow + 0);
                const float4 wb = *reinterpret_cast<const float4*>(wrow + 4);
                const float4 wc = *reinterpret_cast<const float4*>(wrow + 8);
                const float4 wd = *reinterpret_cast<const float4*>(wrow + 12);
                acc[ 0] = fmaf(xa[i], wa.x, acc[ 0]);
                acc[ 1] = fmaf(xa[i], wa.y, acc[ 1]);
                acc[ 2] = fmaf(xa[i], wa.z, acc[ 2]);
                acc[ 3] = fmaf(xa[i], wa.w, acc[ 3]);
                acc[ 4] = fmaf(xa[i], wb.x, acc[ 4]);
                acc[ 5] = fmaf(xa[i], wb.y, acc[ 5]);
                acc[ 6] = fmaf(xa[i], wb.z, acc[ 6]);
                acc[ 7] = fmaf(xa[i], wb.w, acc[ 7]);
                acc[ 8] = fmaf(xa[i], wc.x, acc[ 8]);
                acc[ 9] = fmaf(xa[i], wc.y, acc[ 9]);
                acc[10] = fmaf(xa[i], wc.z, acc[10]);
                acc[11] = fmaf(xa[i], wc.w, acc[11]);
                acc[12] = fmaf(xa[i], wd.x, acc[12]);
                acc[13] = fmaf(xa[i], wd.y, acc[13]);
                acc[14] = fmaf(xa[i], wd.z, acc[14]);
                acc[15] = fmaf(xa[i], wd.w, acc[15]);
            }
        }
        const float xt = xrow[264];
        const float* wrow = w1g + 264*128 + vzero;
        const float4 wa = *reinterpret_cast<const float4*>(wrow + 0);
        const float4 wb = *reinterpret_cast<const float4*>(wrow + 4);
        const float4 wc = *reinterpret_cast<const float4*>(wrow + 8);
        const float4 wd = *reinterpret_cast<const float4*>(wrow + 12);
        acc[ 0] = fmaf(xt, wa.x, acc[ 0]);
        acc[ 1] = fmaf(xt, wa.y, acc[ 1]);
        acc[ 2] = fmaf(xt, wa.z, acc[ 2]);
        acc[ 3] = fmaf(xt, wa.w, acc[ 3]);
        acc[ 4] = fmaf(xt, wb.x, acc[ 4]);
        acc[ 5] = fmaf(xt, wb.y, acc[ 5]);
        acc[ 6] = fmaf(xt, wb.z, acc[ 6]);
        acc[ 7] = fmaf(xt, wb.w, acc[ 7]);
        acc[ 8] = fmaf(xt, wc.x, acc[ 8]);
        acc[ 9] = fmaf(xt, wc.y, acc[ 9]);
        acc[10] = fmaf(xt, wc.z, acc[10]);
        acc[11] = fmaf(xt, wc.w, acc[11]);
        acc[12] = fmaf(xt, wd.x, acc[12]);
        acc[13] = fmaf(xt, wd.y, acc[13]);
        acc[14] = fmaf(xt, wd.z, acc[14]);
        acc[15] = fmaf(xt, wd.w, acc[15]);
    }
    __syncthreads();
    // bias+relu, h1 overlays the dead x-buffer
    {
        float* hrow = xb + lane*HROW + cb;
        #pragma unroll
        for (int q = 0; q < 4; ++q) {
            float4 hv;
            hv.x = fmaxf(acc[q*4+0] + b1[cb+q*4+0], 0.0f);
            hv.y = fmaxf(acc[q*4+1] + b1[cb+q*4+1], 0.0f);
            hv.z = fmaxf(acc[q*4+2] + b1[cb+q*4+2], 0.0f);
            hv.w = fmaxf(acc[q*4+3] + b1[cb+q*4+3], 0.0f);
            *reinterpret_cast<float4*>(hrow + q*4) = hv;
        }
    }
    __syncthreads();

    // ---- layer 2 ----
    float acc2[16];
    #pragma unroll
    for (int jj = 0; jj < 16; ++jj) acc2[jj] = 0.0f;
    {
        const float* __restrict__ w2g = W2 + cb;
        const float* hrow = xb + lane*HROW;
        for (int d4 = 0; d4 < 32; ++d4) {
            const float4 hv = *reinterpret_cast<const float4*>(hrow + d4*4);
            const float ha[4] = {hv.x, hv.y, hv.z, hv.w};
            #pragma unroll
            for (int i = 0; i < 4; ++i) {
                const float* wrow = w2g + (d4*4 + i)*128 + vzero;  // VMEM path
                const float4 wa = *reinterpret_cast<const float4*>(wrow + 0);
                const float4 wb = *reinterpret_cast<const float4*>(wrow + 4);
                const float4 wc = *reinterpret_cast<const float4*>(wrow + 8);
                const float4 wd = *reinterpret_cast<const float4*>(wrow + 12);
                acc2[ 0] = fmaf(ha[i], wa.x, acc2[ 0]);
                acc2[ 1] = fmaf(ha[i], wa.y, acc2[ 1]);
                acc2[ 2] = fmaf(ha[i], wa.z, acc2[ 2]);
                acc2[ 3] = fmaf(ha[i], wa.w, acc2[ 3]);
                acc2[ 4] = fmaf(ha[i], wb.x, acc2[ 4]);
                acc2[ 5] = fmaf(ha[i], wb.y, acc2[ 5]);
                acc2[ 6] = fmaf(ha[i], wb.z, acc2[ 6]);
                acc2[ 7] = fmaf(ha[i], wb.w, acc2[ 7]);
                acc2[ 8] = fmaf(ha[i], wc.x, acc2[ 8]);
                acc2[ 9] = fmaf(ha[i], wc.y, acc2[ 9]);
                acc2[10] = fmaf(ha[i], wc.z, acc2[10]);
                acc2[11] = fmaf(ha[i], wc.w, acc2[11]);
                acc2[12] = fmaf(ha[i], wd.x, acc2[12]);
                acc2[13] = fmaf(ha[i], wd.y, acc2[13]);
                acc2[14] = fmaf(ha[i], wd.z, acc2[14]);
                acc2[15] = fmaf(ha[i], wd.w, acc2[15]);
            }
        }
    }
    // ---- readout partials over this wave's 16 channels ----
    {
        float pk0=0.f, pk1=0.f, pk2=0.f, pk3=0.f;
        #pragma unroll
        for (int jj = 0; jj < 16; ++jj) {
            const float h2 = fmaxf(acc2[jj] + b2[cb+jj], 0.0f);
            const float4 wv = *reinterpret_cast<const float4*>(Wr + (cb+jj)*4 + vzero);
            pk0 = fmaf(h2, wv.x, pk0);
            pk1 = fmaf(h2, wv.y, pk1);
            pk2 = fmaf(h2, wv.z, pk2);
            pk3 = fmaf(h2, wv.w, pk3);
        }
        partials[g][lane][0] = pk0; partials[g][lane][1] = pk1;
        partials[g][lane][2] = pk2; partials[g][lane][3] = pk3;
    }
    __syncthreads();
    if (t < 256) {
        const int s = t >> 2, k = t & 3;
        float sum = 0.0f;
        #pragma unroll
        for (int gg = 0; gg < 8; ++gg) sum += partials[gg][s][k];
        wsout[(bid*NSAMP + s)*4 + k] = sum;
    }
}

// Kernel B: per-ray render. 1 wave per ray; lane = sample.
__global__ __launch_bounds__(64)
void nerf_render(const float* __restrict__ ws,
                 const float* __restrict__ br,
                 float* __restrict__ out)
{
    const int r = blockIdx.x;
    const int p = threadIdx.x;
    constexpr float STEP = (ZFAR - ZNEAR) / (NSAMP - 1);
    const float4 a = *reinterpret_cast<const float4*>(ws + ((r*2+0)*NSAMP + p)*4);
    const float4 b = *reinterpret_cast<const float4*>(ws + ((r*2+1)*NSAMP + p)*4);
    const float o0 = 0.5f*(a.x + b.x) + br[0];
    const float o1 = 0.5f*(a.y + b.y) + br[1];
    const float o2 = 0.5f*(a.z + b.z) + br[2];
    const float o3 = 0.5f*(a.w + b.w) + br[3];
    const float c0 = 1.0f/(1.0f + __expf(-o0));
    const float c1 = 1.0f/(1.0f + __expf(-o1));
    const float c2 = 1.0f/(1.0f + __expf(-o2));
    const float dens = fmaxf(o3, 0.0f);
    const float zp = ZNEAR + p * STEP;
    const float zn = ZNEAR + (p+1) * STEP;
    const float dlast = (ZNEAR + 63*STEP) - (ZNEAR + 62*STEP);
    const float dist = (p == NSAMP-1) ? dlast : (zn - zp);
    const float alpha = 1.0f - __expf(-dens*dist);
    float scan = 1.0f - alpha + 1e-10f;              // inclusive cumprod
    #pragma unroll
    for (int off = 1; off < 64; off <<= 1) {
        const float vsh = __shfl_up(scan, off, 64);
        if (p >= off) scan *= vsh;
    }
    float trans = __shfl_up(scan, 1, 64);            // exclusive
    if (p == 0) trans = 1.0f;
    const float w = alpha * trans;
    float s0 = w*c0, s1 = w*c1, s2 = w*c2, sd = w*zp;
    #pragma unroll
    for (int m = 32; m > 0; m >>= 1) {
        s0 += __shfl_xor(s0, m, 64);
        s1 += __shfl_xor(s1, m, 64);
        s2 += __shfl_xor(s2, m, 64);
        sd += __shfl_xor(sd, m, 64);
    }
    if (p == 0) {
        out[r*3+0] = s0; out[r*3+1] = s1; out[r*3+2] = s2;
        out[NRAYS*3 + r] = sd;
    }
}

extern "C" void kernel_launch(void* const* d_in, const int* in_sizes, int n_in,
                              void* d_out, int out_size, void* d_ws, size_t ws_size,
                              hipStream_t stream) {
    const float* rayo   = (const float*)d_in[0];
    const float* rayd   = (const float*)d_in[1];
    const float* images = (const float*)d_in[2];
    const float* intr   = (const float*)d_in[3];
    const float* einv   = (const float*)d_in[4];
    const float* feats  = (const float*)d_in[5];
    const float* W1     = (const float*)d_in[6];
    const float* b1     = (const float*)d_in[7];
    const float* W2     = (const float*)d_in[8];
    const float* b2     = (const float*)d_in[9];
    const float* Wr     = (const float*)d_in[10];
    const float* br     = (const float*)d_in[11];
    float* out = (float*)d_out;
    float* ws  = (float*)d_ws;

    hipLaunchKernelGGL(nerf_mlp, dim3(NRAYS*NVIEW), dim3(512), 0, stream,
                       rayo, rayd, images, intr, einv, feats,
                       W1, b1, W2, b2, Wr, ws);
    hipLaunchKernelGGL(nerf_render, dim3(NRAYS), dim3(64), 0, stream,
                       ws, br, out);
}

// Round 4
// 136.700 us; speedup vs baseline: 2.8507x; 2.8507x over previous
//
#include <hip/hip_runtime.h>
#include <math.h>

#define NRAYS 512
#define NSAMP 64
#define NVIEW 2
#define IMH 480
#define IMW 640
#define NFEAT 256
#define XROW 268     // 265-dim x row, 67 float4 slots
#define D1 265
#define NCH1 33      // 33 full 8-dim chunks (264 dims) + 1 tail dim
#define NCH2 16      // 128 = 16 x 8
#define H2ROW 132
#define ZNEAR 0.7f
#define ZFAR 1.5f

// Block = (ray, view), 512 threads = 8 waves.
// Phase A: projection + bilinear gather -> x[64][XROW] in LDS (unchanged from R2).
// Phase B: MLP with lane = output channel (j, j+64), wave g = samples [8g,8g+8).
//   Weights stream global -> LDS in 8x128 chunks, double-buffered, one barrier
//   per chunk. All hot-loop memory is in-order LDS: per-lane ds_read_b32 for
//   weights (2 lanes/bank = free) + wave-uniform ds_read_b128 broadcasts for x.
// Phase C: readout partials (lane = sample, wave = 16-ch slice) -> ws.
__global__ __launch_bounds__(512, 4)
void nerf_mlp(const float* __restrict__ rayo,
              const float* __restrict__ rayd,
              const float* __restrict__ images,
              const float* __restrict__ intr,
              const float* __restrict__ einv,
              const float* __restrict__ feats,
              const float* __restrict__ W1,
              const float* __restrict__ b1,
              const float* __restrict__ W2,
              const float* __restrict__ b2,
              const float* __restrict__ Wr,
              float* __restrict__ wsout)
{
    __shared__ float smem[19200];     // xb 17152 | wbuf 2x1024
    __shared__ int   s_off[NSAMP][4];
    __shared__ float s_wxy[NSAMP][2];
    __shared__ float s_cam[NSAMP][4];
    __shared__ float s_cdir[4];

    float* const xb   = smem;                 // [64][268]
    float* const wbuf = smem + 17152;         // [2][1024]
    float* const h1   = smem;                 // [64][128]  overlays xb
    float* const h2   = smem + 8192;          // [64][132]  overlays xb
    float (*const part)[NSAMP][4] = (float(*)[NSAMP][4])(smem + 17152); // overlays wbuf

    const int t = threadIdx.x;
    const int bid = blockIdx.x;
    const int r = bid >> 1;
    const int v = bid & 1;
    const int lane = t & 63;
    const int g = __builtin_amdgcn_readfirstlane(t >> 6);
    const int s0 = g * 8;                     // this wave's 8 samples
    constexpr float STEP = (ZFAR - ZNEAR) / (NSAMP - 1);

    // per-lane biases (channels lane, lane+64)
    const float b1lo = b1[lane], b1hi = b1[lane + 64];
    const float b2lo = b2[lane], b2hi = b2[lane + 64];

    const float ox = rayo[r*3+0], oy = rayo[r*3+1], oz = rayo[r*3+2];
    const float dx = rayd[r*3+0], dy = rayd[r*3+1], dz = rayd[r*3+2];

    // ---- projection prep ----
    if (t < NSAMP) {
        const int p = t;
        const float z = ZNEAR + p * STEP;
        const float wxp = ox + z*dx, wyp = oy + z*dy, wzp = oz + z*dz;
        const float* E = einv + v*16;
        const float cx = E[0]*wxp + E[1]*wyp + E[2]*wzp + E[3];
        const float cy = E[4]*wxp + E[5]*wyp + E[6]*wzp + E[7];
        const float cz = E[8]*wxp + E[9]*wyp + E[10]*wzp + E[11];
        const float cw = E[12]*wxp + E[13]*wyp + E[14]*wzp + E[15];
        const float* Km = intr + v*16;
        const float px = Km[0]*cx + Km[1]*cy + Km[2]*cz + Km[3]*cw;
        const float py = Km[4]*cx + Km[5]*cy + Km[6]*cz + Km[7]*cw;
        const float pz = Km[8]*cx + Km[9]*cy + Km[10]*cz + Km[11]*cw;
        const float inv = pz + 1e-8f;
        float fx = px / inv, fy = py / inv;
        fx = fminf(fmaxf(fx, 0.0f), (float)(IMW-1));
        fy = fminf(fmaxf(fy, 0.0f), (float)(IMH-1));
        const int x0 = (int)floorf(fx), y0 = (int)floorf(fy);
        const int x1 = min(x0+1, IMW-1), y1 = min(y0+1, IMH-1);
        const int base = v*IMH*IMW;
        s_off[p][0] = (base + y0*IMW + x0) * NFEAT;
        s_off[p][1] = (base + y0*IMW + x1) * NFEAT;
        s_off[p][2] = (base + y1*IMW + x0) * NFEAT;
        s_off[p][3] = (base + y1*IMW + x1) * NFEAT;
        s_wxy[p][0] = fx - (float)x0;
        s_wxy[p][1] = fy - (float)y0;
        s_cam[p][0] = cx; s_cam[p][1] = cy; s_cam[p][2] = cz;
        if (t == 0) {
            s_cdir[0] = E[0]*dx + E[1]*dy + E[2]*dz;
            s_cdir[1] = E[4]*dx + E[5]*dy + E[6]*dz;
            s_cdir[2] = E[8]*dx + E[9]*dy + E[10]*dz;
        }
    }
    __syncthreads();

    // prefetch W1 chunk 0 (overlaps the gather below)
    float4 stg;
    if (t < 256) stg = *reinterpret_cast<const float4*>(W1 + t*4);

    // ---- bilinear gather: 8 threads per sample ----
    {
        const int s = t >> 3, k = t & 7;
        const int o00 = s_off[s][0], o01 = s_off[s][1];
        const int o10 = s_off[s][2], o11 = s_off[s][3];
        const float wxf = s_wxy[s][0], wyf = s_wxy[s][1];
        const float w00 = (1.f-wxf)*(1.f-wyf), w01 = wxf*(1.f-wyf);
        const float w10 = (1.f-wxf)*wyf,       w11 = wxf*wyf;
        float* xrow = xb + s * XROW;
        #pragma unroll
        for (int i = 0; i < 8; ++i) {
            const int c = k*32 + i*4;
            const float4 f00 = *reinterpret_cast<const float4*>(feats + o00 + c);
            const float4 f01 = *reinterpret_cast<const float4*>(feats + o01 + c);
            const float4 f10 = *reinterpret_cast<const float4*>(feats + o10 + c);
            const float4 f11 = *reinterpret_cast<const float4*>(feats + o11 + c);
            xrow[9+c+0] = w00*f00.x + w01*f01.x + w10*f10.x + w11*f11.x;
            xrow[9+c+1] = w00*f00.y + w01*f01.y + w10*f10.y + w11*f11.y;
            xrow[9+c+2] = w00*f00.z + w01*f01.z + w10*f10.z + w11*f11.z;
            xrow[9+c+3] = w00*f00.w + w01*f01.w + w10*f10.w + w11*f11.w;
        }
        if (k == 0) {
            const int i00 = (o00 >> 8) * 3, i01 = (o01 >> 8) * 3;
            const int i10 = (o10 >> 8) * 3, i11 = (o11 >> 8) * 3;
            #pragma unroll
            for (int ch = 0; ch < 3; ++ch) {
                const float bl = w00*images[i00+ch] + w01*images[i01+ch]
                               + w10*images[i10+ch] + w11*images[i11+ch];
                xrow[6+ch] = 2.0f*bl - 1.0f;
            }
            xrow[0] = s_cam[s][0]; xrow[1] = s_cam[s][1]; xrow[2] = s_cam[s][2];
        } else if (k == 1) {
            xrow[3] = s_cdir[0]; xrow[4] = s_cdir[1]; xrow[5] = s_cdir[2];
        }
    }
    if (t < 256) *reinterpret_cast<float4*>(wbuf + t*4) = stg;   // chunk0 -> buf0
    __syncthreads();

    // ---- layer 1: 33 chunks of 8 dims, double-buffered ----
    float accL[8], accH[8];
    #pragma unroll
    for (int s = 0; s < 8; ++s) { accL[s] = 0.0f; accH[s] = 0.0f; }
    // hoist tail-dim (264) weights early so the loads pipeline under the loop
    const float wtl = W1[264*128 + lane];
    const float wth = W1[264*128 + 64 + lane];

    for (int c = 0; c < NCH1; ++c) {
        float4 nxt;
        if (c+1 < NCH1 && t < 256)
            nxt = *reinterpret_cast<const float4*>(W1 + (c+1)*1024 + t*4);
        const float* wc = wbuf + (c & 1) * 1024;
        #pragma unroll
        for (int dd = 0; dd < 2; ++dd) {
            const int d0 = c*8 + dd*4;
            float wlo[4], whi[4];
            #pragma unroll
            for (int d = 0; d < 4; ++d) {
                wlo[d] = wc[(dd*4+d)*128 + lane];
                whi[d] = wc[(dd*4+d)*128 + 64 + lane];
            }
            #pragma unroll
            for (int s = 0; s < 8; ++s) {
                const float4 xv = *reinterpret_cast<const float4*>(xb + (s0+s)*XROW + d0);
                accL[s] = fmaf(xv.x, wlo[0], accL[s]);
                accH[s] = fmaf(xv.x, whi[0], accH[s]);
                accL[s] = fmaf(xv.y, wlo[1], accL[s]);
                accH[s] = fmaf(xv.y, whi[1], accH[s]);
                accL[s] = fmaf(xv.z, wlo[2], accL[s]);
                accH[s] = fmaf(xv.z, whi[2], accH[s]);
                accL[s] = fmaf(xv.w, wlo[3], accL[s]);
                accH[s] = fmaf(xv.w, whi[3], accH[s]);
            }
        }
        if (c+1 < NCH1 && t < 256)
            *reinterpret_cast<float4*>(wbuf + ((c+1) & 1) * 1024 + t*4) = nxt;
        __syncthreads();
    }
    // tail dim 264
    #pragma unroll
    for (int s = 0; s < 8; ++s) {
        const float xs = xb[(s0+s)*XROW + 264];
        accL[s] = fmaf(xs, wtl, accL[s]);
        accH[s] = fmaf(xs, wth, accH[s]);
    }
    __syncthreads();                     // all waves done reading xb

    // prefetch W2 chunk 0, write h1 (overlays xb)
    float4 stg2;
    if (t < 256) stg2 = *reinterpret_cast<const float4*>(W2 + t*4);
    #pragma unroll
    for (int s = 0; s < 8; ++s) {
        h1[(s0+s)*128 + lane]      = fmaxf(accL[s] + b1lo, 0.0f);
        h1[(s0+s)*128 + 64 + lane] = fmaxf(accH[s] + b1hi, 0.0f);
    }
    __syncthreads();                     // h1 complete, wbuf free
    if (t < 256) *reinterpret_cast<float4*>(wbuf + t*4) = stg2;
    __syncthreads();

    // ---- layer 2: 16 chunks of 8 dims ----
    float aL[8], aH[8];
    #pragma unroll
    for (int s = 0; s < 8; ++s) { aL[s] = 0.0f; aH[s] = 0.0f; }
    for (int c = 0; c < NCH2; ++c) {
        float4 nxt;
        if (c+1 < NCH2 && t < 256)
            nxt = *reinterpret_cast<const float4*>(W2 + (c+1)*1024 + t*4);
        const float* wc = wbuf + (c & 1) * 1024;
        #pragma unroll
        for (int dd = 0; dd < 2; ++dd) {
            const int d0 = c*8 + dd*4;
            float wlo[4], whi[4];
            #pragma unroll
            for (int d = 0; d < 4; ++d) {
                wlo[d] = wc[(dd*4+d)*128 + lane];
                whi[d] = wc[(dd*4+d)*128 + 64 + lane];
            }
            #pragma unroll
            for (int s = 0; s < 8; ++s) {
                const float4 xv = *reinterpret_cast<const float4*>(h1 + (s0+s)*128 + d0);
                aL[s] = fmaf(xv.x, wlo[0], aL[s]);
                aH[s] = fmaf(xv.x, whi[0], aH[s]);
                aL[s] = fmaf(xv.y, wlo[1], aL[s]);
                aH[s] = fmaf(xv.y, whi[1], aH[s]);
                aL[s] = fmaf(xv.z, wlo[2], aL[s]);
                aH[s] = fmaf(xv.z, whi[2], aH[s]);
                aL[s] = fmaf(xv.w, wlo[3], aL[s]);
                aH[s] = fmaf(xv.w, whi[3], aH[s]);
            }
        }
        if (c+1 < NCH2 && t < 256)
            *reinterpret_cast<float4*>(wbuf + ((c+1) & 1) * 1024 + t*4) = nxt;
        __syncthreads();
    }
    // bias+relu, h2 (region disjoint from h1)
    #pragma unroll
    for (int s = 0; s < 8; ++s) {
        h2[(s0+s)*H2ROW + lane]      = fmaxf(aL[s] + b2lo, 0.0f);
        h2[(s0+s)*H2ROW + 64 + lane] = fmaxf(aH[s] + b2hi, 0.0f);
    }
    __syncthreads();

    // ---- readout: lane = sample, wave g -> channels [16g,16g+16) ----
    {
        const int cb = g * 16;
        float pk0=0.f, pk1=0.f, pk2=0.f, pk3=0.f;
        const float* h2row = h2 + lane * H2ROW;
        #pragma unroll
        for (int jj = 0; jj < 16; ++jj) {
            const float hv = h2row[cb + jj];
            const float4 wv = *reinterpret_cast<const float4*>(Wr + (cb+jj)*4);
            pk0 = fmaf(hv, wv.x, pk0);
            pk1 = fmaf(hv, wv.y, pk1);
            pk2 = fmaf(hv, wv.z, pk2);
            pk3 = fmaf(hv, wv.w, pk3);
        }
        part[g][lane][0] = pk0; part[g][lane][1] = pk1;
        part[g][lane][2] = pk2; part[g][lane][3] = pk3;
    }
    __syncthreads();
    if (t < 256) {
        const int s = t >> 2, k = t & 3;
        float sum = 0.0f;
        #pragma unroll
        for (int gg = 0; gg < 8; ++gg) sum += part[gg][s][k];
        wsout[(bid*NSAMP + s)*4 + k] = sum;
    }
}

// Kernel B: per-ray render. 1 wave per ray; lane = sample.
__global__ __launch_bounds__(64)
void nerf_render(const float* __restrict__ ws,
                 const float* __restrict__ br,
                 float* __restrict__ out)
{
    const int r = blockIdx.x;
    const int p = threadIdx.x;
    constexpr float STEP = (ZFAR - ZNEAR) / (NSAMP - 1);
    const float4 a = *reinterpret_cast<const float4*>(ws + ((r*2+0)*NSAMP + p)*4);
    const float4 b = *reinterpret_cast<const float4*>(ws + ((r*2+1)*NSAMP + p)*4);
    const float o0 = 0.5f*(a.x + b.x) + br[0];
    const float o1 = 0.5f*(a.y + b.y) + br[1];
    const float o2 = 0.5f*(a.z + b.z) + br[2];
    const float o3 = 0.5f*(a.w + b.w) + br[3];
    const float c0 = 1.0f/(1.0f + __expf(-o0));
    const float c1 = 1.0f/(1.0f + __expf(-o1));
    const float c2 = 1.0f/(1.0f + __expf(-o2));
    const float dens = fmaxf(o3, 0.0f);
    const float zp = ZNEAR + p * STEP;
    const float zn = ZNEAR + (p+1) * STEP;
    const float dlast = (ZNEAR + 63*STEP) - (ZNEAR + 62*STEP);
    const float dist = (p == NSAMP-1) ? dlast : (zn - zp);
    const float alpha = 1.0f - __expf(-dens*dist);
    float scan = 1.0f - alpha + 1e-10f;              // inclusive cumprod
    #pragma unroll
    for (int off = 1; off < 64; off <<= 1) {
        const float vsh = __shfl_up(scan, off, 64);
        if (p >= off) scan *= vsh;
    }
    float trans = __shfl_up(scan, 1, 64);            // exclusive
    if (p == 0) trans = 1.0f;
    const float w = alpha * trans;
    float s0 = w*c0, s1 = w*c1, s2 = w*c2, sd = w*zp;
    #pragma unroll
    for (int m = 32; m > 0; m >>= 1) {
        s0 += __shfl_xor(s0, m, 64);
        s1 += __shfl_xor(s1, m, 64);
        s2 += __shfl_xor(s2, m, 64);
        sd += __shfl_xor(sd, m, 64);
    }
    if (p == 0) {
        out[r*3+0] = s0; out[r*3+1] = s1; out[r*3+2] = s2;
        out[NRAYS*3 + r] = sd;
    }
}

extern "C" void kernel_launch(void* const* d_in, const int* in_sizes, int n_in,
                              void* d_out, int out_size, void* d_ws, size_t ws_size,
                              hipStream_t stream) {
    const float* rayo   = (const float*)d_in[0];
    const float* rayd   = (const float*)d_in[1];
    const float* images = (const float*)d_in[2];
    const float* intr   = (const float*)d_in[3];
    const float* einv   = (const float*)d_in[4];
    const float* feats  = (const float*)d_in[5];
    const float* W1     = (const float*)d_in[6];
    const float* b1     = (const float*)d_in[7];
    const float* W2     = (const float*)d_in[8];
    const float* b2     = (const float*)d_in[9];
    const float* Wr     = (const float*)d_in[10];
    const float* br     = (const float*)d_in[11];
    float* out = (float*)d_out;
    float* ws  = (float*)d_ws;

    hipLaunchKernelGGL(nerf_mlp, dim3(NRAYS*NVIEW), dim3(512), 0, stream,
                       rayo, rayd, images, intr, einv, feats,
                       W1, b1, W2, b2, Wr, ws);
    hipLaunchKernelGGL(nerf_render, dim3(NRAYS), dim3(64), 0, stream,
                       ws, br, out);
}

// Round 5
// 109.866 us; speedup vs baseline: 3.5470x; 1.2442x over previous
//
#include <hip/hip_runtime.h>
#include <math.h>

#define NRAYS 512
#define NSAMP 64
#define IMH 480
#define IMW 640
#define NFEAT 256
#define ZNEAR 0.7f
#define ZFAR 1.5f
#define RBU 616          // row-block stride in ushorts (1232 B; 308 dw ≡ 20 mod 32 -> conflict-free)

typedef __attribute__((ext_vector_type(8))) short bf16x8;
typedef __attribute__((ext_vector_type(4))) float f32x4;

__device__ __forceinline__ unsigned short bf16rne(float f) {
    unsigned int u = __builtin_bit_cast(unsigned int, f);
    unsigned int r = (u + 0x7FFFu + ((u >> 16) & 1u)) >> 16;
    return (unsigned short)r;
}
__device__ __forceinline__ float bf16tof(unsigned short h) {
    unsigned int u = ((unsigned int)h) << 16;
    return __builtin_bit_cast(float, u);
}
// write split pair (v0,v1) at ushort offset p (even): hi plane at p, lo plane at p+288
__device__ __forceinline__ void wsplit2(unsigned short* p, float v0, float v1) {
    unsigned short h0 = bf16rne(v0), h1 = bf16rne(v1);
    float l0 = v0 - bf16tof(h0), l1 = v1 - bf16tof(h1);
    *(unsigned int*)(p)       = (unsigned int)h0 | ((unsigned int)h1 << 16);
    *(unsigned int*)(p + 288) = (unsigned int)bf16rne(l0) | ((unsigned int)bf16rne(l1) << 16);
}

// ---- prep: transpose + bf16-split W1 (265x128 -> [128][288] with pad@9, k>=266=0) and W2 ----
// ws ushort layout: W1h @0 (128*288) | W1l @36864 | W2h @73728 (128*128) | W2l @90112
__global__ __launch_bounds__(256)
void nerf_prep(const float* __restrict__ W1, const float* __restrict__ W2,
               unsigned short* __restrict__ wsu) {
    const int i = blockIdx.x * 256 + threadIdx.x;
    if (i < 36864) {
        const int n = i / 288, k = i % 288;
        float val = 0.0f;
        if (k < 9) val = W1[k * 128 + n];
        else if (k >= 10 && k <= 265) val = W1[(k - 1) * 128 + n];
        const unsigned short h = bf16rne(val);
        wsu[n * 288 + k] = h;
        wsu[36864 + n * 288 + k] = bf16rne(val - bf16tof(h));
    } else if (i < 53248) {
        const int j = i - 36864;
        const int n = j >> 7, k = j & 127;
        const float val = W2[k * 128 + n];
        const unsigned short h = bf16rne(val);
        wsu[73728 + n * 128 + k] = h;
        wsu[90112 + n * 128 + k] = bf16rne(val - bf16tof(h));
    }
}

// ---- main: block = (ray,view), 256 thr = 4 waves. Gather -> split-bf16 LDS x,
// then 3-pass MFMA MLP (B-frags from global, barrier-free), readout -> partials.
__global__ __launch_bounds__(256, 2)
void nerf_main(const float* __restrict__ rayo,
               const float* __restrict__ rayd,
               const float* __restrict__ images,
               const float* __restrict__ intr,
               const float* __restrict__ einv,
               const float* __restrict__ feats,
               const float* __restrict__ b1,
               const float* __restrict__ b2,
               const float* __restrict__ Wr,
               const unsigned short* __restrict__ wsu,
               float* __restrict__ pf) {
    __shared__ unsigned short xbs[NSAMP * RBU];    // 78,848 B

    const int t = threadIdx.x;
    const int bid = blockIdx.x;
    const int r = bid >> 1, v = bid & 1;
    const int lane = t & 63;
    const int wid = __builtin_amdgcn_readfirstlane(t >> 6);   // wave = M-tile
    constexpr float STEP = (ZFAR - ZNEAR) / (NSAMP - 1);

    const float ox = rayo[r*3+0], oy = rayo[r*3+1], oz = rayo[r*3+2];
    const float dx = rayd[r*3+0], dy = rayd[r*3+1], dz = rayd[r*3+2];

    // ---- projection prep: one thread per sample ----
    if (t < NSAMP) {
        const int p = t;
        const float z = ZNEAR + p * STEP;
        const float wxp = ox + z*dx, wyp = oy + z*dy, wzp = oz + z*dz;
        const float* E = einv + v*16;
        const float cx = E[0]*wxp + E[1]*wyp + E[2]*wzp + E[3];
        const float cy = E[4]*wxp + E[5]*wyp + E[6]*wzp + E[7];
        const float cz = E[8]*wxp + E[9]*wyp + E[10]*wzp + E[11];
        const float cw = E[12]*wxp + E[13]*wyp + E[14]*wzp + E[15];
        const float* Km = intr + v*16;
        const float px = Km[0]*cx + Km[1]*cy + Km[2]*cz + Km[3]*cw;
        const float py = Km[4]*cx + Km[5]*cy + Km[6]*cz + Km[7]*cw;
        const float pz = Km[8]*cx + Km[9]*cy + Km[10]*cz + Km[11]*cw;
        const float inv = pz + 1e-8f;
        float fx = px / inv, fy = py / inv;
        fx = fminf(fmaxf(fx, 0.0f), (float)(IMW-1));
        fy = fminf(fmaxf(fy, 0.0f), (float)(IMH-1));
        const int x0 = (int)floorf(fx), y0 = (int)floorf(fy);
        const int x1 = min(x0+1, IMW-1), y1 = min(y0+1, IMH-1);
        const int base = v*IMH*IMW;
        char* rowc = (char*)(xbs + p * RBU);
        int4 o4; o4.x = (base + y0*IMW + x0) * NFEAT;
                 o4.y = (base + y0*IMW + x1) * NFEAT;
                 o4.z = (base + y1*IMW + x0) * NFEAT;
                 o4.w = (base + y1*IMW + x1) * NFEAT;
        *(int4*)(rowc + 1152) = o4;
        float2 wxy; wxy.x = fx - (float)x0; wxy.y = fy - (float)y0;
        *(float2*)(rowc + 1168) = wxy;
        // cam dir (per-thread redundant compute, cheap)
        const float cdx = E[0]*dx + E[1]*dy + E[2]*dz;
        const float cdy = E[4]*dx + E[5]*dy + E[6]*dz;
        const float cdz = E[8]*dx + E[9]*dy + E[10]*dz;
        unsigned short* xr = (unsigned short*)rowc;
        wsplit2(xr + 0, cx,  cy);
        wsplit2(xr + 2, cz,  cdx);
        wsplit2(xr + 4, cdy, cdz);
        // zero k-pad 266..287, both planes
        #pragma unroll
        for (int i = 0; i < 11; ++i) {
            *(unsigned int*)(rowc +  532 + 4*i) = 0u;
            *(unsigned int*)(rowc + 1108 + 4*i) = 0u;
        }
    }
    __syncthreads();

    // ---- bilinear gather: 4 threads/sample, split-bf16 writes ----
    {
        const int s = t >> 2, k = t & 3;
        char* rowc = (char*)(xbs + s * RBU);
        const int4 o4 = *(const int4*)(rowc + 1152);
        const float2 wxy = *(const float2*)(rowc + 1168);
        const float w00 = (1.f-wxy.x)*(1.f-wxy.y), w01 = wxy.x*(1.f-wxy.y);
        const float w10 = (1.f-wxy.x)*wxy.y,       w11 = wxy.x*wxy.y;
        unsigned short* xr = (unsigned short*)rowc;
        const int cbase = k * 64;
        #pragma unroll
        for (int i = 0; i < 16; ++i) {
            const int c = cbase + i*4;
            const float4 f00 = *reinterpret_cast<const float4*>(feats + o4.x + c);
            const float4 f01 = *reinterpret_cast<const float4*>(feats + o4.y + c);
            const float4 f10 = *reinterpret_cast<const float4*>(feats + o4.z + c);
            const float4 f11 = *reinterpret_cast<const float4*>(feats + o4.w + c);
            const float v0 = w00*f00.x + w01*f01.x + w10*f10.x + w11*f11.x;
            const float v1 = w00*f00.y + w01*f01.y + w10*f10.y + w11*f11.y;
            const float v2 = w00*f00.z + w01*f01.z + w10*f10.z + w11*f11.z;
            const float v3 = w00*f00.w + w01*f01.w + w10*f10.w + w11*f11.w;
            wsplit2(xr + 10 + c,     v0, v1);
            wsplit2(xr + 10 + c + 2, v2, v3);
        }
        if (k == 0) {
            const int i00 = (o4.x >> 8) * 3, i01 = (o4.y >> 8) * 3;
            const int i10 = (o4.z >> 8) * 3, i11 = (o4.w >> 8) * 3;
            float im[3];
            #pragma unroll
            for (int ch = 0; ch < 3; ++ch) {
                const float bl = w00*images[i00+ch] + w01*images[i01+ch]
                               + w10*images[i10+ch] + w11*images[i11+ch];
                im[ch] = 2.0f*bl - 1.0f;
            }
            wsplit2(xr + 6, im[0], im[1]);
            wsplit2(xr + 8, im[2], 0.0f);     // dim 9 = pad
        }
    }
    __syncthreads();

    // ---- MFMA MLP (no barriers from here to the end) ----
    const int l15 = lane & 15;
    const int lg  = lane >> 4;
    const int koff = lg * 8;                        // ushorts
    const int arow = wid * 16 + l15;
    const unsigned short* rowb = xbs + arow * RBU;
    const int hr0 = wid * 16 + lg * 4;

    // layer 1: A-frags (x) preloaded; B-frags (W1 split) streamed from global
    bf16x8 a1h[9], a1l[9];
    #pragma unroll
    for (int kc = 0; kc < 9; ++kc) {
        a1h[kc] = *(const bf16x8*)(rowb + kc*32 + koff);
        a1l[kc] = *(const bf16x8*)(rowb + 288 + kc*32 + koff);
    }
    const unsigned short* wb1 = wsu + l15 * 288 + koff;
    #pragma unroll 2
    for (int nt = 0; nt < 8; ++nt) {
        const unsigned short* wp = wb1 + nt * 16 * 288;
        f32x4 acc = {0.f, 0.f, 0.f, 0.f};
        #pragma unroll
        for (int kc = 0; kc < 9; ++kc) {
            const bf16x8 bh = *(const bf16x8*)(wp + kc*32);
            const bf16x8 bl = *(const bf16x8*)(wp + 36864 + kc*32);
            acc = __builtin_amdgcn_mfma_f32_16x16x32_bf16(a1h[kc], bh, acc, 0, 0, 0);
            acc = __builtin_amdgcn_mfma_f32_16x16x32_bf16(a1l[kc], bh, acc, 0, 0, 0);
            acc = __builtin_amdgcn_mfma_f32_16x16x32_bf16(a1h[kc], bl, acc, 0, 0, 0);
        }
        const int ch = nt * 16 + l15;
        const float bb = b1[ch];
        #pragma unroll
        for (int j = 0; j < 4; ++j) {
            const float hv = fmaxf(acc[j] + bb, 0.0f);
            const unsigned short hh = bf16rne(hv);
            const unsigned short hl = bf16rne(hv - bf16tof(hh));
            unsigned short* hb = xbs + (hr0 + j) * RBU + ch;   // overlay own rows
            hb[0]   = hh;
            hb[288] = hl;
        }
    }

    // layer 2: A-frags from h1 (own rows, no barrier needed)
    bf16x8 a2h[4], a2l[4];
    #pragma unroll
    for (int kc = 0; kc < 4; ++kc) {
        a2h[kc] = *(const bf16x8*)(rowb + kc*32 + koff);
        a2l[kc] = *(const bf16x8*)(rowb + 288 + kc*32 + koff);
    }
    float pr[4][4];
    #pragma unroll
    for (int j = 0; j < 4; ++j)
        #pragma unroll
        for (int q = 0; q < 4; ++q) pr[j][q] = 0.0f;

    const unsigned short* wb2 = wsu + 73728 + l15 * 128 + koff;
    #pragma unroll 2
    for (int nt = 0; nt < 8; ++nt) {
        const unsigned short* wp = wb2 + nt * 16 * 128;
        f32x4 acc = {0.f, 0.f, 0.f, 0.f};
        #pragma unroll
        for (int kc = 0; kc < 4; ++kc) {
            const bf16x8 bh = *(const bf16x8*)(wp + kc*32);
            const bf16x8 bl = *(const bf16x8*)(wp + 16384 + kc*32);
            acc = __builtin_amdgcn_mfma_f32_16x16x32_bf16(a2h[kc], bh, acc, 0, 0, 0);
            acc = __builtin_amdgcn_mfma_f32_16x16x32_bf16(a2l[kc], bh, acc, 0, 0, 0);
            acc = __builtin_amdgcn_mfma_f32_16x16x32_bf16(a2h[kc], bl, acc, 0, 0, 0);
        }
        const int ch = nt * 16 + l15;
        const float bb = b2[ch];
        const float4 wr = *reinterpret_cast<const float4*>(Wr + ch * 4);
        #pragma unroll
        for (int j = 0; j < 4; ++j) {
            const float hv = fmaxf(acc[j] + bb, 0.0f);
            pr[j][0] = fmaf(hv, wr.x, pr[j][0]);
            pr[j][1] = fmaf(hv, wr.y, pr[j][1]);
            pr[j][2] = fmaf(hv, wr.z, pr[j][2]);
            pr[j][3] = fmaf(hv, wr.w, pr[j][3]);
        }
    }
    // reduce the 16 lanes (channel slices) of each lane-group
    #pragma unroll
    for (int m = 1; m <= 8; m <<= 1)
        #pragma unroll
        for (int j = 0; j < 4; ++j)
            #pragma unroll
            for (int q = 0; q < 4; ++q)
                pr[j][q] += __shfl_xor(pr[j][q], m, 64);
    if (l15 == 0) {
        #pragma unroll
        for (int j = 0; j < 4; ++j) {
            float4 o;
            o.x = pr[j][0]; o.y = pr[j][1]; o.z = pr[j][2]; o.w = pr[j][3];
            *reinterpret_cast<float4*>(pf + ((size_t)bid * 64 + hr0 + j) * 4) = o;
        }
    }
}

// ---- render: per-ray, lane = sample ----
__global__ __launch_bounds__(64)
void nerf_render(const float* __restrict__ pf,
                 const float* __restrict__ br,
                 float* __restrict__ out) {
    const int r = blockIdx.x;
    const int p = threadIdx.x;
    constexpr float STEP = (ZFAR - ZNEAR) / (NSAMP - 1);
    const float4 a = *reinterpret_cast<const float4*>(pf + ((r*2+0)*NSAMP + p)*4);
    const float4 b = *reinterpret_cast<const float4*>(pf + ((r*2+1)*NSAMP + p)*4);
    const float o0 = 0.5f*(a.x + b.x) + br[0];
    const float o1 = 0.5f*(a.y + b.y) + br[1];
    const float o2 = 0.5f*(a.z + b.z) + br[2];
    const float o3 = 0.5f*(a.w + b.w) + br[3];
    const float c0 = 1.0f/(1.0f + __expf(-o0));
    const float c1 = 1.0f/(1.0f + __expf(-o1));
    const float c2 = 1.0f/(1.0f + __expf(-o2));
    const float dens = fmaxf(o3, 0.0f);
    const float zp = ZNEAR + p * STEP;
    const float zn = ZNEAR + (p+1) * STEP;
    const float dlast = (ZNEAR + 63*STEP) - (ZNEAR + 62*STEP);
    const float dist = (p == NSAMP-1) ? dlast : (zn - zp);
    const float alpha = 1.0f - __expf(-dens*dist);
    float scan = 1.0f - alpha + 1e-10f;
    #pragma unroll
    for (int off = 1; off < 64; off <<= 1) {
        const float vsh = __shfl_up(scan, off, 64);
        if (p >= off) scan *= vsh;
    }
    float trans = __shfl_up(scan, 1, 64);
    if (p == 0) trans = 1.0f;
    const float w = alpha * trans;
    float s0 = w*c0, s1 = w*c1, s2 = w*c2, sd = w*zp;
    #pragma unroll
    for (int m = 32; m > 0; m >>= 1) {
        s0 += __shfl_xor(s0, m, 64);
        s1 += __shfl_xor(s1, m, 64);
        s2 += __shfl_xor(s2, m, 64);
        sd += __shfl_xor(sd, m, 64);
    }
    if (p == 0) {
        out[r*3+0] = s0; out[r*3+1] = s1; out[r*3+2] = s2;
        out[NRAYS*3 + r] = sd;
    }
}

extern "C" void kernel_launch(void* const* d_in, const int* in_sizes, int n_in,
                              void* d_out, int out_size, void* d_ws, size_t ws_size,
                              hipStream_t stream) {
    const float* rayo   = (const float*)d_in[0];
    const float* rayd   = (const float*)d_in[1];
    const float* images = (const float*)d_in[2];
    const float* intr   = (const float*)d_in[3];
    const float* einv   = (const float*)d_in[4];
    const float* feats  = (const float*)d_in[5];
    const float* W1     = (const float*)d_in[6];
    const float* b1     = (const float*)d_in[7];
    const float* W2     = (const float*)d_in[8];
    const float* b2     = (const float*)d_in[9];
    const float* Wr     = (const float*)d_in[10];
    const float* br     = (const float*)d_in[11];
    float* out = (float*)d_out;
    unsigned short* wsu = (unsigned short*)d_ws;                 // W split planes (213 KB)
    float* pf = (float*)((char*)d_ws + 262144);                  // partials (1 MB)

    hipLaunchKernelGGL(nerf_prep, dim3(208), dim3(256), 0, stream, W1, W2, wsu);
    hipLaunchKernelGGL(nerf_main, dim3(NRAYS*2), dim3(256), 0, stream,
                       rayo, rayd, images, intr, einv, feats, b1, b2, Wr, wsu, pf);
    hipLaunchKernelGGL(nerf_render, dim3(NRAYS), dim3(64), 0, stream, pf, br, out);
}